// Round 9
// baseline (746.741 us; speedup 1.0000x reference)
//
#include <hip/hip_runtime.h>
#include <hip/hip_fp16.h>
#include <cstdint>
#include <cstddef>

#define NN 50000
#define NE 800000
#define HD 64
#define SB 49       // scan blocks = ceil(50000/1024)
#define NQUAD 12500 // node quads

// ---------------- CSR build: histogram ----------------
__global__ void k_hist(const int* __restrict__ ei, int* __restrict__ cnt) {
    int e = blockIdx.x * blockDim.x + threadIdx.x;
    if (e < NE) atomicAdd(&cnt[ei[NE + e]], 1);
}

// ------- hierarchical scan, phase 1: per-block local exclusive scan -------
__global__ __launch_bounds__(256) void k_scan1(const int* __restrict__ cnt,
                                               int* __restrict__ row_start,
                                               int* __restrict__ bsum) {
    __shared__ int ssum[256];
    const int tid = threadIdx.x, b = blockIdx.x;
    const int i0 = b * 1024 + tid * 4;
    int c0 = 0, c1 = 0, c2 = 0, c3 = 0;
    if (i0 + 3 < NN) {
        const int4 c = *(const int4*)(cnt + i0);
        c0 = c.x; c1 = c.y; c2 = c.z; c3 = c.w;
    } else {
        if (i0 + 0 < NN) c0 = cnt[i0 + 0];
        if (i0 + 1 < NN) c1 = cnt[i0 + 1];
        if (i0 + 2 < NN) c2 = cnt[i0 + 2];
        if (i0 + 3 < NN) c3 = cnt[i0 + 3];
    }
    ssum[tid] = c0 + c1 + c2 + c3;
    __syncthreads();
    for (int off = 1; off < 256; off <<= 1) {
        int v = (tid >= off) ? ssum[tid - off] : 0;
        __syncthreads();
        ssum[tid] += v;
        __syncthreads();
    }
    int ex = (tid == 0) ? 0 : ssum[tid - 1];
    if (i0 + 0 < NN) row_start[i0 + 0] = ex;
    ex += c0;
    if (i0 + 1 < NN) row_start[i0 + 1] = ex;
    ex += c1;
    if (i0 + 2 < NN) row_start[i0 + 2] = ex;
    ex += c2;
    if (i0 + 3 < NN) row_start[i0 + 3] = ex;
    if (tid == 255) bsum[b] = ssum[255];
}

// ------- scan phase 2: scan the 49 block sums -------
__global__ __launch_bounds__(64) void k_scan2(const int* __restrict__ bsum,
                                              int* __restrict__ boff,
                                              int* __restrict__ row_start) {
    __shared__ int s[64];
    const int t = threadIdx.x;
    s[t] = (t < SB) ? bsum[t] : 0;
    __syncthreads();
    for (int off = 1; off < 64; off <<= 1) {
        int v = (t >= off) ? s[t - off] : 0;
        __syncthreads();
        s[t] += v;
        __syncthreads();
    }
    if (t < SB) boff[t] = (t == 0) ? 0 : s[t - 1];
    if (t == 0) row_start[NN] = s[SB - 1];  // = NE
}

// ------- scan phase 3: add block offsets; init cur = row_start -------
__global__ __launch_bounds__(256) void k_scan3(int* __restrict__ row_start,
                                               const int* __restrict__ boff,
                                               int* __restrict__ cur) {
    const int b = blockIdx.x;
    const int i0 = b * 1024 + threadIdx.x * 4;
    const int o = boff[b];
#pragma unroll
    for (int k = 0; k < 4; ++k) {
        int i = i0 + k;
        if (i < NN) {
            int v = row_start[i] + o;
            row_start[i] = v;
            cur[i] = v;
        }
    }
}

// ------- CSR scatter: ONE 16 B record per edge, dst-sorted (1 edge/thread) ----
// rec = { h2(e0,e1), h2(e2,e3), (src<<16)|h(e4), 0 }
__global__ void k_scatter(const int* __restrict__ ei, const float* __restrict__ ea,
                          int* __restrict__ cur, uint4* __restrict__ e5p) {
    int e = blockIdx.x * blockDim.x + threadIdx.x;
    if (e < NE) {
        int d = ei[NE + e];
        int pos = atomicAdd(&cur[d], 1);
        const float e0 = __logf(ea[(size_t)e * 5 + 0] + 1.f);
        const float e1 = __logf(ea[(size_t)e * 5 + 1] + 1.f);
        const float e2 = __logf(ea[(size_t)e * 5 + 2] + 1.f);
        const float e3 = __logf(ea[(size_t)e * 5 + 3] + 1.f);
        const float e4 = __logf(ea[(size_t)e * 5 + 4] + 1.f);
        union { __half2 h; unsigned u; } c01, c23;
        c01.h = __floats2half2_rn(e0, e1);
        c23.h = __floats2half2_rn(e2, e3);
        uint4 rec;
        rec.x = c01.u;
        rec.y = c23.u;
        rec.z = ((unsigned)ei[e] << 16) |
                (unsigned)__half_as_ushort(__float2half_rn(e4));
        rec.w = 0u;
        e5p[pos] = rec;
    }
}

// kv row layout: dword d holds half2 {k[d], v[d]} for dim d (d=0..63).
__device__ __forceinline__ void cvt_kv(const uint4 u, float4& k4, float4& v4) {
    const float2 p0 = __half22float2(*(const __half2*)&u.x);
    const float2 p1 = __half22float2(*(const __half2*)&u.y);
    const float2 p2 = __half22float2(*(const __half2*)&u.z);
    const float2 p3 = __half22float2(*(const __half2*)&u.w);
    k4 = make_float4(p0.x, p1.x, p2.x, p3.x);
    v4 = make_float4(p0.y, p1.y, p2.y, p3.y);
}

// ------- fused 4-matrix GEMM, DIN=10 (layer 1, log1p fused at staging) -------
__global__ __launch_bounds__(256, 4) void k_qkvs10(
    const float* __restrict__ x,
    const float* __restrict__ Wq, const float* __restrict__ Bq,
    const float* __restrict__ Wk, const float* __restrict__ Bk,
    const float* __restrict__ Wv, const float* __restrict__ Bv,
    const float* __restrict__ Ws, const float* __restrict__ Bs,
    float* __restrict__ qb, __half* __restrict__ kvh, float* __restrict__ sb) {
    __shared__ float xs[640];
    const int lane = threadIdx.x & 63;
    const int w = threadIdx.x >> 6;
    const bool iskv = (w == 1 || w == 3);
    const float* WA = (w == 0) ? Wq : iskv ? Wk : Ws;
    const float* BA = (w == 0) ? Bq : iskv ? Bk : Bs;
    const float scl = (w == 0) ? 0.125f : 1.f;  // fold logit scale into q
    float wrA[10], wrB[10];
#pragma unroll
    for (int j = 0; j < 10; ++j) {
        wrA[j] = WA[j * 64 + lane] * scl;
        wrB[j] = iskv ? Wv[j * 64 + lane] : 0.f;
    }
    const float bA = BA[lane] * scl;
    const float bB = iskv ? Bv[lane] : 0.f;
    const int tile = blockIdx.x;
    const int fbase = tile * 640;
    const int fcnt = min(640, NN * 10 - fbase);
    if (threadIdx.x * 4 < fcnt) {
        float4 v = *(const float4*)(x + (size_t)fbase + threadIdx.x * 4);
        v.x = __logf(v.x + 1.f);
        v.y = __logf(v.y + 1.f);
        v.z = __logf(v.z + 1.f);
        v.w = __logf(v.w + 1.f);
        *(float4*)&xs[threadIdx.x * 4] = v;
    }
    __syncthreads();
    const int nbase = tile * 64;
    const int nodes = min(64, NN - nbase);
    const int n0 = (w == 3) ? 32 : 0;
    const int n1 = iskv ? ((w == 1) ? min(nodes, 32) : nodes) : nodes;
    for (int n = n0; n < n1; ++n) {
        float accA = bA, accB = bB;
#pragma unroll
        for (int j = 0; j < 10; ++j) {
            const float xv = xs[n * 10 + j];
            accA = fmaf(xv, wrA[j], accA);
            accB = fmaf(xv, wrB[j], accB);
        }
        const size_t node = (size_t)(nbase + n);
        if (iskv) {
            const __half2 hv = __floats2half2_rn(accA, accB);  // {k, v}
            *(__half2*)(kvh + node * 128 + lane * 2) = hv;
        } else if (w == 0) {
            qb[node * 64 + lane] = accA;
        } else {
            sb[node * 64 + lane] = accA;
        }
    }
}

// ---- fused agg + next-layer 4-matrix GEMM, PERSISTENT over node quads ----
// !FINAL: grid 1024 (4 blocks/CU resident). Each wave loads its weight matrix
// (64 VGPRs) ONCE, then the block grid-strides over ~12 quads: phase 1 = 16x4
// defer-max aggregation (one node/wave) -> o; phase 2 = next-layer q/k/v/s
// GEMM from LDS-staged o with resident weights. Weight L2 traffic returns to
// qkvs64 levels (67 MB/layer vs 820 MB in the round-8 per-quad version).
// FINAL: grid NQUAD, single pass, output linear, no weights.
template <bool FINAL>
__global__ __launch_bounds__(256, 4) void k_agg(
    const float* __restrict__ q, const __half* __restrict__ kv,
    const float* __restrict__ sk, const uint4* __restrict__ e5p,
    const float* __restrict__ wE, const int* __restrict__ row_start,
    float* __restrict__ hout, const float* __restrict__ lw, const float* lb,
    const float* __restrict__ Wq, const float* __restrict__ Bq,
    const float* __restrict__ Wk, const float* __restrict__ Bk,
    const float* __restrict__ Wv, const float* __restrict__ Bv,
    const float* __restrict__ Ws, const float* __restrict__ Bs,
    float* __restrict__ qout, __half* __restrict__ kvout,
    float* __restrict__ sout) {
    __shared__ float ols[256];  // 4 nodes x 64 dims (layer output)
    __shared__ float kls[256];  // 4 nodes x 64 dims (k pass to v-wave)
    const int lane = threadIdx.x & 63;
    const int wave = threadIdx.x >> 6;
    const int g = lane >> 4, t = lane & 15;
    // resident next-layer weights (one matrix per wave)
    float wr[64];
    float bias = 0.f;
    if (!FINAL) {
        const float* W = (wave == 0) ? Wq : (wave == 1) ? Ws : (wave == 2) ? Wk : Wv;
        const float* B = (wave == 0) ? Bq : (wave == 1) ? Bs : (wave == 2) ? Bk : Bv;
        const float wscl = (wave == 0) ? 0.125f : 1.f;
#pragma unroll
        for (int j = 0; j < 64; ++j) wr[j] = W[j * 64 + lane] * wscl;
        bias = B[lane] * wscl;
    }
    for (int quad = blockIdx.x; quad < NQUAD; quad += gridDim.x) {
        const int node = __builtin_amdgcn_readfirstlane(quad * 4 + wave);
        const int beg = row_start[node], end = row_start[node + 1];
        const float4 s4 = *(const float4*)(sk + (size_t)node * 64 + t * 4);
        float4 o4;
        if (beg == end) {
            o4 = s4;
        } else {
            const float4 q4 = *(const float4*)(q + (size_t)node * 64 + t * 4);
            // g5: group g computes dot64(q, wE row g); group 0 also row 4.
            float g5[5];
            {
                const float4 wg = *(const float4*)(wE + g * 64 + t * 4);
                float dc = q4.x * wg.x;
                dc = fmaf(q4.y, wg.y, dc);
                dc = fmaf(q4.z, wg.z, dc);
                dc = fmaf(q4.w, wg.w, dc);
                dc += __shfl_xor(dc, 1);
                dc += __shfl_xor(dc, 2);
                dc += __shfl_xor(dc, 4);
                dc += __shfl_xor(dc, 8);
                const float4 w4 = *(const float4*)(wE + 4 * 64 + t * 4);
                float d4 = q4.x * w4.x;
                d4 = fmaf(q4.y, w4.y, d4);
                d4 = fmaf(q4.z, w4.z, d4);
                d4 = fmaf(q4.w, w4.w, d4);
                d4 += __shfl_xor(d4, 1);
                d4 += __shfl_xor(d4, 2);
                d4 += __shfl_xor(d4, 4);
                d4 += __shfl_xor(d4, 8);
                g5[0] = __shfl(dc, 0);
                g5[1] = __shfl(dc, 16);
                g5[2] = __shfl(dc, 32);
                g5[3] = __shfl(dc, 48);
                g5[4] = __shfl(d4, 0);
            }
            // per-group deferred-max softmax state
            float m = -1e30f, l = 0.f;
            float4 accv = {0.f, 0.f, 0.f, 0.f};
            float a50 = 0.f, a51 = 0.f, a52 = 0.f, a53 = 0.f, a54 = 0.f;
            const char* kvc = (const char*)kv;
            const int i0x = beg + g;
            const int i0 = (i0x < end) ? i0x : beg;
            uint4 r0 = e5p[i0];
            const int i1x = beg + 4 + g;
            const int i1 = (i1x < end) ? i1x : beg;
            uint4 r1 = e5p[i1];
            uint4 kv8 =
                *(const uint4*)(kvc + (size_t)((r0.z & 0xffff0000u) >> 8) + t * 16);
#pragma unroll 2
            for (int p = beg; p < end; p += 4) {
                const int nx = p + 8 + g;
                const int npp = (nx < end) ? nx : beg;
                const uint4 rn = e5p[npp];
                const uint4 nkv = *(const uint4*)(
                    kvc + (size_t)((r1.z & 0xffff0000u) >> 8) + t * 16);
                const bool act = (p + g) < end;
                float4 k4, v4;
                cvt_kv(kv8, k4, v4);
                const float2 e01 = __half22float2(*(const __half2*)&r0.x);
                const float2 e23 = __half22float2(*(const __half2*)&r0.y);
                const float e4v =
                    __half2float(__ushort_as_half((unsigned short)(r0.z & 0xffffu)));
                float d = q4.x * k4.x;
                d = fmaf(q4.y, k4.y, d);
                d = fmaf(q4.z, k4.z, d);
                d = fmaf(q4.w, k4.w, d);
                d += __shfl_xor(d, 1);
                d += __shfl_xor(d, 2);
                d += __shfl_xor(d, 4);
                d += __shfl_xor(d, 8);
                float d5 = g5[0] * e01.x;
                d5 = fmaf(g5[1], e01.y, d5);
                d5 = fmaf(g5[2], e23.x, d5);
                d5 = fmaf(g5[3], e23.y, d5);
                d5 = fmaf(g5[4], e4v, d5);
                const float la = act ? (d + d5) : -__builtin_inff();
                float pa = __expf(la - m);
                if (la > m + 8.f) {  // group-uniform
                    const float rs = __expf(m - la);
                    l *= rs;
                    accv.x *= rs;
                    accv.y *= rs;
                    accv.z *= rs;
                    accv.w *= rs;
                    a50 *= rs;
                    a51 *= rs;
                    a52 *= rs;
                    a53 *= rs;
                    a54 *= rs;
                    m = la;
                    pa = 1.f;
                }
                l += pa;
                accv.x = fmaf(pa, v4.x, accv.x);
                accv.y = fmaf(pa, v4.y, accv.y);
                accv.z = fmaf(pa, v4.z, accv.z);
                accv.w = fmaf(pa, v4.w, accv.w);
                a50 = fmaf(pa, e01.x, a50);
                a51 = fmaf(pa, e01.y, a51);
                a52 = fmaf(pa, e23.x, a52);
                a53 = fmaf(pa, e23.y, a53);
                a54 = fmaf(pa, e4v, a54);
                r0 = r1;
                r1 = rn;
                kv8 = nkv;
            }
            // ---- merge the 4 per-group states (flash-style) ----
            float M = fmaxf(m, __shfl_xor(m, 16));
            M = fmaxf(M, __shfl_xor(M, 32));
            const float f = __expf(m - M);
            float lz = l * f;
            lz += __shfl_xor(lz, 16);
            lz += __shfl_xor(lz, 32);
            accv.x *= f;
            accv.y *= f;
            accv.z *= f;
            accv.w *= f;
            a50 *= f;
            a51 *= f;
            a52 *= f;
            a53 *= f;
            a54 *= f;
#pragma unroll
            for (int s = 16; s <= 32; s <<= 1) {
                accv.x += __shfl_xor(accv.x, s);
                accv.y += __shfl_xor(accv.y, s);
                accv.z += __shfl_xor(accv.z, s);
                accv.w += __shfl_xor(accv.w, s);
                a50 += __shfl_xor(a50, s);
                a51 += __shfl_xor(a51, s);
                a52 += __shfl_xor(a52, s);
                a53 += __shfl_xor(a53, s);
                a54 += __shfl_xor(a54, s);
            }
            // fold edge-feature accumulator back through wE; add skip
            float4 t4 = accv;
            {
                const float4 w0 = *(const float4*)(wE + 0 * 64 + t * 4);
                const float4 w1 = *(const float4*)(wE + 1 * 64 + t * 4);
                const float4 w2 = *(const float4*)(wE + 2 * 64 + t * 4);
                const float4 w3 = *(const float4*)(wE + 3 * 64 + t * 4);
                const float4 w4r = *(const float4*)(wE + 4 * 64 + t * 4);
                t4.x = fmaf(a50, w0.x, t4.x);
                t4.y = fmaf(a50, w0.y, t4.y);
                t4.z = fmaf(a50, w0.z, t4.z);
                t4.w = fmaf(a50, w0.w, t4.w);
                t4.x = fmaf(a51, w1.x, t4.x);
                t4.y = fmaf(a51, w1.y, t4.y);
                t4.z = fmaf(a51, w1.z, t4.z);
                t4.w = fmaf(a51, w1.w, t4.w);
                t4.x = fmaf(a52, w2.x, t4.x);
                t4.y = fmaf(a52, w2.y, t4.y);
                t4.z = fmaf(a52, w2.z, t4.z);
                t4.w = fmaf(a52, w2.w, t4.w);
                t4.x = fmaf(a53, w3.x, t4.x);
                t4.y = fmaf(a53, w3.y, t4.y);
                t4.z = fmaf(a53, w3.z, t4.z);
                t4.w = fmaf(a53, w3.w, t4.w);
                t4.x = fmaf(a54, w4r.x, t4.x);
                t4.y = fmaf(a54, w4r.y, t4.y);
                t4.z = fmaf(a54, w4r.z, t4.z);
                t4.w = fmaf(a54, w4r.w, t4.w);
            }
            const float rl = 1.f / lz;
            o4.x = fmaf(t4.x, rl, s4.x);
            o4.y = fmaf(t4.y, rl, s4.y);
            o4.z = fmaf(t4.z, rl, s4.z);
            o4.w = fmaf(t4.w, rl, s4.w);
        }
        if (FINAL) {
            const float4 lw4 = *(const float4*)(lw + t * 4);
            float r = o4.x * lw4.x;
            r = fmaf(o4.y, lw4.y, r);
            r = fmaf(o4.z, lw4.z, r);
            r = fmaf(o4.w, lw4.w, r);
            r += __shfl_xor(r, 1);
            r += __shfl_xor(r, 2);
            r += __shfl_xor(r, 4);
            r += __shfl_xor(r, 8);
            if (lane == 0) hout[node] = r + lb[0];
            continue;
        }
        // ---- phase 2: next-layer q/k/v/s GEMM from LDS-staged o ----
        if (g == 0) *(float4*)&ols[wave * 64 + t * 4] = o4;
        __syncthreads();
        float acc[4] = {bias, bias, bias, bias};
#pragma unroll
        for (int jq = 0; jq < 16; ++jq) {
#pragma unroll
            for (int n = 0; n < 4; ++n) {
                const float4 xv = *(const float4*)&ols[n * 64 + jq * 4];  // bcast
                acc[n] = fmaf(xv.x, wr[jq * 4 + 0], acc[n]);
                acc[n] = fmaf(xv.y, wr[jq * 4 + 1], acc[n]);
                acc[n] = fmaf(xv.z, wr[jq * 4 + 2], acc[n]);
                acc[n] = fmaf(xv.w, wr[jq * 4 + 3], acc[n]);
            }
        }
        if (wave == 2) {
#pragma unroll
            for (int n = 0; n < 4; ++n) kls[n * 64 + lane] = acc[n];
        }
        __syncthreads();
        const int nb = quad * 4;
        if (wave == 0) {
#pragma unroll
            for (int n = 0; n < 4; ++n) qout[(size_t)(nb + n) * 64 + lane] = acc[n];
        } else if (wave == 1) {
#pragma unroll
            for (int n = 0; n < 4; ++n) sout[(size_t)(nb + n) * 64 + lane] = acc[n];
        } else if (wave == 3) {
#pragma unroll
            for (int n = 0; n < 4; ++n) {
                const float kk = kls[n * 64 + lane];
                *(__half2*)(kvout + (size_t)(nb + n) * 128 + lane * 2) =
                    __floats2half2_rn(kk, acc[n]);
            }
        }
    }
}

extern "C" void kernel_launch(void* const* d_in, const int* in_sizes, int n_in,
                              void* d_out, int out_size, void* d_ws, size_t ws_size,
                              hipStream_t stream) {
    const float* x = (const float*)d_in[0];
    const int* ei = (const int*)d_in[1];
    const float* ea = (const float*)d_in[2];
    const float* w1q = (const float*)d_in[3];
    const float* b1q = (const float*)d_in[4];
    const float* w1k = (const float*)d_in[5];
    const float* b1k = (const float*)d_in[6];
    const float* w1v = (const float*)d_in[7];
    const float* b1v = (const float*)d_in[8];
    const float* w1e = (const float*)d_in[9];
    const float* w1s = (const float*)d_in[10];
    const float* b1s = (const float*)d_in[11];
    const float* wq = (const float*)d_in[12];
    const float* bq = (const float*)d_in[13];
    const float* wk = (const float*)d_in[14];
    const float* bk = (const float*)d_in[15];
    const float* wv = (const float*)d_in[16];
    const float* bv = (const float*)d_in[17];
    const float* we = (const float*)d_in[18];
    const float* ws = (const float*)d_in[19];
    const float* bs = (const float*)d_in[20];
    const float* lw = (const float*)d_in[21];
    const float* lb = (const float*)d_in[22];

    // ---- workspace carve (256B aligned), ~90 MB ----
    uintptr_t p = (uintptr_t)d_ws;
    auto alloc = [&](size_t bytes) -> void* {
        void* r = (void*)p;
        p += (bytes + 255) & ~(size_t)255;
        return r;
    };
    uint4* e5p = (uint4*)alloc((size_t)NE * 16);          // 12.8 MB dst-sorted recs
    float* qA = (float*)alloc((size_t)NN * HD * 4);       // 12.8 MB
    float* qB = (float*)alloc((size_t)NN * HD * 4);
    float* sA = (float*)alloc((size_t)NN * HD * 4);
    float* sB = (float*)alloc((size_t)NN * HD * 4);
    __half* kvA = (__half*)alloc((size_t)NN * 128 * 2);   // 12.8 MB fp16 pairs
    __half* kvB = (__half*)alloc((size_t)NN * 128 * 2);
    int* row_start = (int*)alloc((size_t)(NN + 1) * 4);
    int* cnt = (int*)alloc((size_t)NN * 4);
    int* cur = (int*)alloc((size_t)NN * 4);
    int* bsum = (int*)alloc((size_t)SB * 4);
    int* boff = (int*)alloc((size_t)SB * 4);

    // ---- preprocess (once per call) ----
    hipMemsetAsync(cnt, 0, (size_t)NN * 4, stream);
    k_hist<<<(NE + 255) / 256, 256, 0, stream>>>(ei, cnt);
    k_scan1<<<SB, 256, 0, stream>>>(cnt, row_start, bsum);
    k_scan2<<<1, 64, 0, stream>>>(bsum, boff, row_start);
    k_scan3<<<SB, 256, 0, stream>>>(row_start, boff, cur);
    k_scatter<<<(NE + 255) / 256, 256, 0, stream>>>(ei, ea, cur, e5p);

    const int gg10 = (NN + 63) / 64;  // 782
    const int persist_grid = 1024;    // 4 blocks/CU resident, ~12 quads/block

    // ---- layer 1 (DIN=10, log1p fused) -> set A ----
    k_qkvs10<<<gg10, 256, 0, stream>>>(x, w1q, b1q, w1k, b1k, w1v, b1v, w1s, b1s,
                                       qA, kvA, sA);

    // ---- fused agg+GEMM chain: agg layer k, produce layer k+1 q/k/v/s ----
    const float* wEs[6] = {w1e, we, we + 320, we + 640, we + 960, we + 1280};
    float* qin = qA;  float* qo = qB;
    float* sin_ = sA; float* so = sB;
    __half* kvin = kvA; __half* kvo = kvB;
    for (int k = 0; k < 5; ++k) {
        k_agg<false><<<persist_grid, 256, 0, stream>>>(
            qin, kvin, sin_, e5p, wEs[k], row_start, nullptr, lw, lb,
            wq + k * 4096, bq + k * 64, wk + k * 4096, bk + k * 64,
            wv + k * 4096, bv + k * 64, ws + k * 4096, bs + k * 64,
            qo, kvo, so);
        float* tf;  __half* th;
        tf = qin; qin = qo; qo = tf;
        tf = sin_; sin_ = so; so = tf;
        th = kvin; kvin = kvo; kvo = th;
    }
    // ---- final layer: agg + output linear ----
    k_agg<true><<<NQUAD, 256, 0, stream>>>(
        qin, kvin, sin_, e5p, wEs[5], row_start, (float*)d_out, lw, lb,
        wq, bq, wk, bk, wv, bv, ws, bs, qo, kvo, so);
}

// Round 10
// 611.236 us; speedup vs baseline: 1.2217x; 1.2217x over previous
//
#include <hip/hip_runtime.h>
#include <hip/hip_fp16.h>
#include <cstdint>
#include <cstddef>

#define NN 50000
#define NE 800000
#define HD 64
#define SB 49      // scan blocks = ceil(50000/1024)
#define NT64 6250  // qkvs64 tiles of 8 nodes

// ---------------- CSR build: histogram ----------------
__global__ void k_hist(const int* __restrict__ ei, int* __restrict__ cnt) {
    int e = blockIdx.x * blockDim.x + threadIdx.x;
    if (e < NE) atomicAdd(&cnt[ei[NE + e]], 1);
}

// ------- hierarchical scan, phase 1: per-block local exclusive scan -------
__global__ __launch_bounds__(256) void k_scan1(const int* __restrict__ cnt,
                                               int* __restrict__ row_start,
                                               int* __restrict__ bsum) {
    __shared__ int ssum[256];
    const int tid = threadIdx.x, b = blockIdx.x;
    const int i0 = b * 1024 + tid * 4;
    int c0 = 0, c1 = 0, c2 = 0, c3 = 0;
    if (i0 + 3 < NN) {
        const int4 c = *(const int4*)(cnt + i0);
        c0 = c.x; c1 = c.y; c2 = c.z; c3 = c.w;
    } else {
        if (i0 + 0 < NN) c0 = cnt[i0 + 0];
        if (i0 + 1 < NN) c1 = cnt[i0 + 1];
        if (i0 + 2 < NN) c2 = cnt[i0 + 2];
        if (i0 + 3 < NN) c3 = cnt[i0 + 3];
    }
    ssum[tid] = c0 + c1 + c2 + c3;
    __syncthreads();
    for (int off = 1; off < 256; off <<= 1) {
        int v = (tid >= off) ? ssum[tid - off] : 0;
        __syncthreads();
        ssum[tid] += v;
        __syncthreads();
    }
    int ex = (tid == 0) ? 0 : ssum[tid - 1];
    if (i0 + 0 < NN) row_start[i0 + 0] = ex;
    ex += c0;
    if (i0 + 1 < NN) row_start[i0 + 1] = ex;
    ex += c1;
    if (i0 + 2 < NN) row_start[i0 + 2] = ex;
    ex += c2;
    if (i0 + 3 < NN) row_start[i0 + 3] = ex;
    if (tid == 255) bsum[b] = ssum[255];
}

// ------- scan phase 2: scan the 49 block sums -------
__global__ __launch_bounds__(64) void k_scan2(const int* __restrict__ bsum,
                                              int* __restrict__ boff,
                                              int* __restrict__ row_start) {
    __shared__ int s[64];
    const int t = threadIdx.x;
    s[t] = (t < SB) ? bsum[t] : 0;
    __syncthreads();
    for (int off = 1; off < 64; off <<= 1) {
        int v = (t >= off) ? s[t - off] : 0;
        __syncthreads();
        s[t] += v;
        __syncthreads();
    }
    if (t < SB) boff[t] = (t == 0) ? 0 : s[t - 1];
    if (t == 0) row_start[NN] = s[SB - 1];  // = NE
}

// ------- scan phase 3: add block offsets; init cur = row_start -------
__global__ __launch_bounds__(256) void k_scan3(int* __restrict__ row_start,
                                               const int* __restrict__ boff,
                                               int* __restrict__ cur) {
    const int b = blockIdx.x;
    const int i0 = b * 1024 + threadIdx.x * 4;
    const int o = boff[b];
#pragma unroll
    for (int k = 0; k < 4; ++k) {
        int i = i0 + k;
        if (i < NN) {
            int v = row_start[i] + o;
            row_start[i] = v;
            cur[i] = v;
        }
    }
}

// ------- CSR scatter: ONE 16 B record per edge, dst-sorted (1 edge/thread) ----
// rec = { h2(e0,e1), h2(e2,e3), (src<<16)|h(e4), 0 }
__global__ void k_scatter(const int* __restrict__ ei, const float* __restrict__ ea,
                          int* __restrict__ cur, uint4* __restrict__ e5p) {
    int e = blockIdx.x * blockDim.x + threadIdx.x;
    if (e < NE) {
        int d = ei[NE + e];
        int pos = atomicAdd(&cur[d], 1);
        const float e0 = __logf(ea[(size_t)e * 5 + 0] + 1.f);
        const float e1 = __logf(ea[(size_t)e * 5 + 1] + 1.f);
        const float e2 = __logf(ea[(size_t)e * 5 + 2] + 1.f);
        const float e3 = __logf(ea[(size_t)e * 5 + 3] + 1.f);
        const float e4 = __logf(ea[(size_t)e * 5 + 4] + 1.f);
        union { __half2 h; unsigned u; } c01, c23;
        c01.h = __floats2half2_rn(e0, e1);
        c23.h = __floats2half2_rn(e2, e3);
        uint4 rec;
        rec.x = c01.u;
        rec.y = c23.u;
        rec.z = ((unsigned)ei[e] << 16) |
                (unsigned)__half_as_ushort(__float2half_rn(e4));
        rec.w = 0u;
        e5p[pos] = rec;
    }
}

// kv row layout: dword d holds half2 {k[d], v[d]} for dim d (d=0..63).
__device__ __forceinline__ void cvt_kv(const uint4 u, float4& k4, float4& v4) {
    const float2 p0 = __half22float2(*(const __half2*)&u.x);
    const float2 p1 = __half22float2(*(const __half2*)&u.y);
    const float2 p2 = __half22float2(*(const __half2*)&u.z);
    const float2 p3 = __half22float2(*(const __half2*)&u.w);
    k4 = make_float4(p0.x, p1.x, p2.x, p3.x);
    v4 = make_float4(p0.y, p1.y, p2.y, p3.y);
}

// ------- fused 4-matrix GEMM, DIN=64: 1 matrix/wave, shared x-tile -------
// Separate kernel (NOT fused into agg): rounds 8/9 measured that fusion
// either loses weight amortization (820 MB L2 refetch) or, made persistent,
// loses occupancy + L2 kv-reuse density. Keep separate.
__global__ __launch_bounds__(256, 4) void k_qkvs64(
    const float* __restrict__ h,
    const float* __restrict__ Wq, const float* __restrict__ Bq,
    const float* __restrict__ Wk, const float* __restrict__ Bk,
    const float* __restrict__ Wv, const float* __restrict__ Bv,
    const float* __restrict__ Ws, const float* __restrict__ Bs,
    float* __restrict__ qb, __half* __restrict__ kvh, float* __restrict__ sb) {
    __shared__ float xs[2][512];
    __shared__ float kls[512];
    const int lane = threadIdx.x & 63;
    const int w = threadIdx.x >> 6;
    const float* W = (w == 0) ? Wq : (w == 1) ? Ws : (w == 2) ? Wk : Wv;
    const float* B = (w == 0) ? Bq : (w == 1) ? Bs : (w == 2) ? Bk : Bv;
    const float scl = (w == 0) ? 0.125f : 1.f;  // fold logit scale into q
    float wr[64];
#pragma unroll
    for (int j = 0; j < 64; ++j) wr[j] = W[j * 64 + lane] * scl;
    const float bias = B[lane] * scl;

    int tile = blockIdx.x;
    {
        const float2 g = *(const float2*)(h + (size_t)tile * 512 + threadIdx.x * 2);
        *(float2*)&xs[0][threadIdx.x * 2] = g;
    }
    __syncthreads();
    int buf = 0;
    while (true) {
        const int nt = tile + gridDim.x;
        const bool more = nt < NT64;
        float2 gn;
        if (more) gn = *(const float2*)(h + (size_t)nt * 512 + threadIdx.x * 2);
        float acc[8] = {bias, bias, bias, bias, bias, bias, bias, bias};
#pragma unroll
        for (int jq = 0; jq < 16; ++jq) {
#pragma unroll
            for (int n = 0; n < 8; ++n) {
                const float4 xv = *(const float4*)&xs[buf][n * 64 + jq * 4];
                acc[n] = fmaf(xv.x, wr[jq * 4 + 0], acc[n]);
                acc[n] = fmaf(xv.y, wr[jq * 4 + 1], acc[n]);
                acc[n] = fmaf(xv.z, wr[jq * 4 + 2], acc[n]);
                acc[n] = fmaf(xv.w, wr[jq * 4 + 3], acc[n]);
            }
        }
        if (w == 2) {
#pragma unroll
            for (int n = 0; n < 8; ++n) kls[n * 64 + lane] = acc[n];
        }
        if (more) *(float2*)&xs[buf ^ 1][threadIdx.x * 2] = gn;
        __syncthreads();
        const int nb = tile * 8;
        if (w == 0) {
#pragma unroll
            for (int n = 0; n < 8; ++n) qb[(size_t)(nb + n) * 64 + lane] = acc[n];
        } else if (w == 1) {
#pragma unroll
            for (int n = 0; n < 8; ++n) sb[(size_t)(nb + n) * 64 + lane] = acc[n];
        } else if (w == 3) {
#pragma unroll
            for (int n = 0; n < 8; ++n) {
                const float kk = kls[n * 64 + lane];
                *(__half2*)(kvh + (size_t)(nb + n) * 128 + lane * 2) =
                    __floats2half2_rn(kk, acc[n]);
            }
        }
        if (!more) break;
        __syncthreads();  // kls + xs[buf^1] reuse fence
        tile = nt;
        buf ^= 1;
    }
}

// ------- fused 4-matrix GEMM, DIN=10 (layer 1, log1p fused at staging) -------
__global__ __launch_bounds__(256, 4) void k_qkvs10(
    const float* __restrict__ x,
    const float* __restrict__ Wq, const float* __restrict__ Bq,
    const float* __restrict__ Wk, const float* __restrict__ Bk,
    const float* __restrict__ Wv, const float* __restrict__ Bv,
    const float* __restrict__ Ws, const float* __restrict__ Bs,
    float* __restrict__ qb, __half* __restrict__ kvh, float* __restrict__ sb) {
    __shared__ float xs[640];
    const int lane = threadIdx.x & 63;
    const int w = threadIdx.x >> 6;
    const bool iskv = (w == 1 || w == 3);
    const float* WA = (w == 0) ? Wq : iskv ? Wk : Ws;
    const float* BA = (w == 0) ? Bq : iskv ? Bk : Bs;
    const float scl = (w == 0) ? 0.125f : 1.f;  // fold logit scale into q
    float wrA[10], wrB[10];
#pragma unroll
    for (int j = 0; j < 10; ++j) {
        wrA[j] = WA[j * 64 + lane] * scl;
        wrB[j] = iskv ? Wv[j * 64 + lane] : 0.f;
    }
    const float bA = BA[lane] * scl;
    const float bB = iskv ? Bv[lane] : 0.f;
    const int tile = blockIdx.x;
    const int fbase = tile * 640;
    const int fcnt = min(640, NN * 10 - fbase);
    if (threadIdx.x * 4 < fcnt) {
        float4 v = *(const float4*)(x + (size_t)fbase + threadIdx.x * 4);
        v.x = __logf(v.x + 1.f);
        v.y = __logf(v.y + 1.f);
        v.z = __logf(v.z + 1.f);
        v.w = __logf(v.w + 1.f);
        *(float4*)&xs[threadIdx.x * 4] = v;
    }
    __syncthreads();
    const int nbase = tile * 64;
    const int nodes = min(64, NN - nbase);
    const int n0 = (w == 3) ? 32 : 0;
    const int n1 = iskv ? ((w == 1) ? min(nodes, 32) : nodes) : nodes;
    for (int n = n0; n < n1; ++n) {
        float accA = bA, accB = bB;
#pragma unroll
        for (int j = 0; j < 10; ++j) {
            const float xv = xs[n * 10 + j];
            accA = fmaf(xv, wrA[j], accA);
            accB = fmaf(xv, wrB[j], accB);
        }
        const size_t node = (size_t)(nbase + n);
        if (iskv) {
            const __half2 hv = __floats2half2_rn(accA, accB);  // {k, v}
            *(__half2*)(kvh + node * 128 + lane * 2) = hv;
        } else if (w == 0) {
            qb[node * 64 + lane] = accA;
        } else {
            sb[node * 64 + lane] = accA;
        }
    }
}

// ---------------- per-dst-node online-softmax aggregation ----------------
// 16x4 structure + DEFER-MAX (round-5 winner, unchanged — best measured).
template <bool FINAL>
__global__ __launch_bounds__(256) void k_agg(
    const float* __restrict__ q, const __half* __restrict__ kv,
    const float* __restrict__ sk, const uint4* __restrict__ e5p,
    const float* __restrict__ wE, const int* __restrict__ row_start,
    float* __restrict__ hout, const float* __restrict__ lw, const float* lb) {
    const int lane = threadIdx.x & 63;
    const int g = lane >> 4, t = lane & 15;
    const int node = __builtin_amdgcn_readfirstlane(blockIdx.x * 4 + (threadIdx.x >> 6));
    if (node >= NN) return;
    const int beg = row_start[node], end = row_start[node + 1];
    if (beg == end) {
        const float4 s4 = *(const float4*)(sk + (size_t)node * 64 + t * 4);
        if (FINAL) {
            const float4 lw4 = *(const float4*)(lw + t * 4);
            float r = s4.x * lw4.x;
            r = fmaf(s4.y, lw4.y, r);
            r = fmaf(s4.z, lw4.z, r);
            r = fmaf(s4.w, lw4.w, r);
            r += __shfl_xor(r, 1);
            r += __shfl_xor(r, 2);
            r += __shfl_xor(r, 4);
            r += __shfl_xor(r, 8);
            if (lane == 0) hout[node] = r + lb[0];
        } else if (g == 0) {
            *(float4*)(hout + (size_t)node * 64 + t * 4) = s4;
        }
        return;
    }
    const float4 q4 = *(const float4*)(q + (size_t)node * 64 + t * 4);  // pre-scaled
    // g5: group g computes dot64(q, wE row g); group 0 also row 4; broadcast.
    float g5[5];
    {
        const float4 wg = *(const float4*)(wE + g * 64 + t * 4);
        float dc = q4.x * wg.x;
        dc = fmaf(q4.y, wg.y, dc);
        dc = fmaf(q4.z, wg.z, dc);
        dc = fmaf(q4.w, wg.w, dc);
        dc += __shfl_xor(dc, 1);
        dc += __shfl_xor(dc, 2);
        dc += __shfl_xor(dc, 4);
        dc += __shfl_xor(dc, 8);
        const float4 w4 = *(const float4*)(wE + 4 * 64 + t * 4);
        float d4 = q4.x * w4.x;
        d4 = fmaf(q4.y, w4.y, d4);
        d4 = fmaf(q4.z, w4.z, d4);
        d4 = fmaf(q4.w, w4.w, d4);
        d4 += __shfl_xor(d4, 1);
        d4 += __shfl_xor(d4, 2);
        d4 += __shfl_xor(d4, 4);
        d4 += __shfl_xor(d4, 8);
        g5[0] = __shfl(dc, 0);
        g5[1] = __shfl(dc, 16);
        g5[2] = __shfl(dc, 32);
        g5[3] = __shfl(dc, 48);
        g5[4] = __shfl(d4, 0);
    }
    // per-group deferred-max softmax state
    float m = -1e30f, l = 0.f;
    float4 accv = {0.f, 0.f, 0.f, 0.f};
    float a50 = 0.f, a51 = 0.f, a52 = 0.f, a53 = 0.f, a54 = 0.f;
    const char* kvc = (const char*)kv;
    // pipeline preamble: e5 2-deep, kv 1-deep
    const int i0x = beg + g;
    const int i0 = (i0x < end) ? i0x : beg;
    uint4 r0 = e5p[i0];
    const int i1x = beg + 4 + g;
    const int i1 = (i1x < end) ? i1x : beg;
    uint4 r1 = e5p[i1];
    uint4 kv8 =
        *(const uint4*)(kvc + (size_t)((r0.z & 0xffff0000u) >> 8) + t * 16);
#pragma unroll 2
    for (int p = beg; p < end; p += 4) {
        // e5 prefetch for iter p+8 (sequential, L2-friendly)
        const int nx = p + 8 + g;
        const int npp = (nx < end) ? nx : beg;
        const uint4 rn = e5p[npp];
        // kv gather for iter p+4 (r1 landed one iter ago)
        const uint4 nkv =
            *(const uint4*)(kvc + (size_t)((r1.z & 0xffff0000u) >> 8) + t * 16);
        // compute current edge
        const bool act = (p + g) < end;
        float4 k4, v4;
        cvt_kv(kv8, k4, v4);
        const float2 e01 = __half22float2(*(const __half2*)&r0.x);
        const float2 e23 = __half22float2(*(const __half2*)&r0.y);
        const float e4v =
            __half2float(__ushort_as_half((unsigned short)(r0.z & 0xffffu)));
        float d = q4.x * k4.x;
        d = fmaf(q4.y, k4.y, d);
        d = fmaf(q4.z, k4.z, d);
        d = fmaf(q4.w, k4.w, d);
        d += __shfl_xor(d, 1);
        d += __shfl_xor(d, 2);
        d += __shfl_xor(d, 4);
        d += __shfl_xor(d, 8);
        float d5 = g5[0] * e01.x;
        d5 = fmaf(g5[1], e01.y, d5);
        d5 = fmaf(g5[2], e23.x, d5);
        d5 = fmaf(g5[3], e23.y, d5);
        d5 = fmaf(g5[4], e4v, d5);
        // inactive slots: la = -INF so pa = 0 with no extra select
        const float la = act ? (d + d5) : -__builtin_inff();
        float pa = __expf(la - m);  // may be +inf pre-first-rescale; discarded
        if (la > m + 8.f) {         // group-uniform (la, m uniform within group)
            const float rs = __expf(m - la);  // 0 on first active edge
            l *= rs;
            accv.x *= rs;
            accv.y *= rs;
            accv.z *= rs;
            accv.w *= rs;
            a50 *= rs;
            a51 *= rs;
            a52 *= rs;
            a53 *= rs;
            a54 *= rs;
            m = la;
            pa = 1.f;
        }
        l += pa;
        accv.x = fmaf(pa, v4.x, accv.x);
        accv.y = fmaf(pa, v4.y, accv.y);
        accv.z = fmaf(pa, v4.z, accv.z);
        accv.w = fmaf(pa, v4.w, accv.w);
        a50 = fmaf(pa, e01.x, a50);
        a51 = fmaf(pa, e01.y, a51);
        a52 = fmaf(pa, e23.x, a52);
        a53 = fmaf(pa, e23.y, a53);
        a54 = fmaf(pa, e4v, a54);
        // rotate pipeline
        r0 = r1;
        r1 = rn;
        kv8 = nkv;
    }
    // ---- merge the 4 per-group states (flash-style) ----
    float M = fmaxf(m, __shfl_xor(m, 16));
    M = fmaxf(M, __shfl_xor(M, 32));
    const float f = __expf(m - M);  // 0 for never-active groups
    float lz = l * f;
    lz += __shfl_xor(lz, 16);
    lz += __shfl_xor(lz, 32);
    accv.x *= f;
    accv.y *= f;
    accv.z *= f;
    accv.w *= f;
    a50 *= f;
    a51 *= f;
    a52 *= f;
    a53 *= f;
    a54 *= f;
#pragma unroll
    for (int s = 16; s <= 32; s <<= 1) {
        accv.x += __shfl_xor(accv.x, s);
        accv.y += __shfl_xor(accv.y, s);
        accv.z += __shfl_xor(accv.z, s);
        accv.w += __shfl_xor(accv.w, s);
        a50 += __shfl_xor(a50, s);
        a51 += __shfl_xor(a51, s);
        a52 += __shfl_xor(a52, s);
        a53 += __shfl_xor(a53, s);
        a54 += __shfl_xor(a54, s);
    }
    // fold edge-feature accumulator back through wE; add skip
    float4 t4 = accv;
    {
        const float4 w0 = *(const float4*)(wE + 0 * 64 + t * 4);
        const float4 w1 = *(const float4*)(wE + 1 * 64 + t * 4);
        const float4 w2 = *(const float4*)(wE + 2 * 64 + t * 4);
        const float4 w3 = *(const float4*)(wE + 3 * 64 + t * 4);
        const float4 w4r = *(const float4*)(wE + 4 * 64 + t * 4);
        t4.x = fmaf(a50, w0.x, t4.x);
        t4.y = fmaf(a50, w0.y, t4.y);
        t4.z = fmaf(a50, w0.z, t4.z);
        t4.w = fmaf(a50, w0.w, t4.w);
        t4.x = fmaf(a51, w1.x, t4.x);
        t4.y = fmaf(a51, w1.y, t4.y);
        t4.z = fmaf(a51, w1.z, t4.z);
        t4.w = fmaf(a51, w1.w, t4.w);
        t4.x = fmaf(a52, w2.x, t4.x);
        t4.y = fmaf(a52, w2.y, t4.y);
        t4.z = fmaf(a52, w2.z, t4.z);
        t4.w = fmaf(a52, w2.w, t4.w);
        t4.x = fmaf(a53, w3.x, t4.x);
        t4.y = fmaf(a53, w3.y, t4.y);
        t4.z = fmaf(a53, w3.z, t4.z);
        t4.w = fmaf(a53, w3.w, t4.w);
        t4.x = fmaf(a54, w4r.x, t4.x);
        t4.y = fmaf(a54, w4r.y, t4.y);
        t4.z = fmaf(a54, w4r.z, t4.z);
        t4.w = fmaf(a54, w4r.w, t4.w);
    }
    const float4 s4 = *(const float4*)(sk + (size_t)node * 64 + t * 4);
    const float rl = 1.f / lz;
    float4 o;
    o.x = fmaf(t4.x, rl, s4.x);
    o.y = fmaf(t4.y, rl, s4.y);
    o.z = fmaf(t4.z, rl, s4.z);
    o.w = fmaf(t4.w, rl, s4.w);
    if (FINAL) {
        const float4 lw4 = *(const float4*)(lw + t * 4);
        float r = o.x * lw4.x;
        r = fmaf(o.y, lw4.y, r);
        r = fmaf(o.z, lw4.z, r);
        r = fmaf(o.w, lw4.w, r);
        r += __shfl_xor(r, 1);
        r += __shfl_xor(r, 2);
        r += __shfl_xor(r, 4);
        r += __shfl_xor(r, 8);
        if (lane == 0) hout[node] = r + lb[0];
    } else if (g == 0) {
        *(float4*)(hout + (size_t)node * 64 + t * 4) = o;
    }
}

extern "C" void kernel_launch(void* const* d_in, const int* in_sizes, int n_in,
                              void* d_out, int out_size, void* d_ws, size_t ws_size,
                              hipStream_t stream) {
    const float* x = (const float*)d_in[0];
    const int* ei = (const int*)d_in[1];
    const float* ea = (const float*)d_in[2];
    const float* w1q = (const float*)d_in[3];
    const float* b1q = (const float*)d_in[4];
    const float* w1k = (const float*)d_in[5];
    const float* b1k = (const float*)d_in[6];
    const float* w1v = (const float*)d_in[7];
    const float* b1v = (const float*)d_in[8];
    const float* w1e = (const float*)d_in[9];
    const float* w1s = (const float*)d_in[10];
    const float* b1s = (const float*)d_in[11];
    const float* wq = (const float*)d_in[12];
    const float* bq = (const float*)d_in[13];
    const float* wk = (const float*)d_in[14];
    const float* bk = (const float*)d_in[15];
    const float* wv = (const float*)d_in[16];
    const float* bv = (const float*)d_in[17];
    const float* we = (const float*)d_in[18];
    const float* ws = (const float*)d_in[19];
    const float* bs = (const float*)d_in[20];
    const float* lw = (const float*)d_in[21];
    const float* lb = (const float*)d_in[22];

    // ---- workspace carve (256B aligned), ~64 MB ----
    uintptr_t p = (uintptr_t)d_ws;
    auto alloc = [&](size_t bytes) -> void* {
        void* r = (void*)p;
        p += (bytes + 255) & ~(size_t)255;
        return r;
    };
    uint4* e5p = (uint4*)alloc((size_t)NE * 16);         // 12.8 MB dst-sorted recs
    float* hb = (float*)alloc((size_t)NN * HD * 4);      // 12.8 MB
    __half* kvh = (__half*)alloc((size_t)NN * 128 * 2);  // 12.8 MB fp16 (k,v) pairs
    float* qb = (float*)alloc((size_t)NN * HD * 4);
    float* sb = (float*)alloc((size_t)NN * HD * 4);
    int* row_start = (int*)alloc((size_t)(NN + 1) * 4);
    int* cnt = (int*)alloc((size_t)NN * 4);
    int* cur = (int*)alloc((size_t)NN * 4);
    int* bsum = (int*)alloc((size_t)SB * 4);
    int* boff = (int*)alloc((size_t)SB * 4);

    // ---- preprocess (once per call) ----
    hipMemsetAsync(cnt, 0, (size_t)NN * 4, stream);
    k_hist<<<(NE + 255) / 256, 256, 0, stream>>>(ei, cnt);
    k_scan1<<<SB, 256, 0, stream>>>(cnt, row_start, bsum);
    k_scan2<<<1, 64, 0, stream>>>(bsum, boff, row_start);
    k_scan3<<<SB, 256, 0, stream>>>(row_start, boff, cur);
    k_scatter<<<(NE + 255) / 256, 256, 0, stream>>>(ei, ea, cur, e5p);

    const int gg64 = 1024;              // 4 blocks/CU at VGPR<=128
    const int gg10 = (NN + 63) / 64;    // 782
    const int agg_grid = (NN + 3) / 4;  // 12500

    // ---- layer 1 (DIN=10, log1p fused) ----
    k_qkvs10<<<gg10, 256, 0, stream>>>(x, w1q, b1q, w1k, b1k, w1v, b1v, w1s, b1s,
                                       qb, kvh, sb);
    k_agg<false><<<agg_grid, 256, 0, stream>>>(qb, kvh, sb, e5p, w1e, row_start,
                                               hb, lw, lb);

    // ---- layers 2..6 (DIN=64); last layer fuses the output linear ----
    for (int i = 0; i < 5; ++i) {
        k_qkvs64<<<gg64, 256, 0, stream>>>(hb, wq + i * 4096, bq + i * 64,
                                           wk + i * 4096, bk + i * 64,
                                           wv + i * 4096, bv + i * 64,
                                           ws + i * 4096, bs + i * 64,
                                           qb, kvh, sb);
        if (i < 4) {
            k_agg<false><<<agg_grid, 256, 0, stream>>>(qb, kvh, sb, e5p,
                                                       we + i * 320, row_start, hb,
                                                       lw, lb);
        } else {
            k_agg<true><<<agg_grid, 256, 0, stream>>>(qb, kvh, sb, e5p,
                                                      we + i * 320, row_start,
                                                      (float*)d_out, lw, lb);
        }
    }
}